// Round 6
// baseline (631.062 us; speedup 1.0000x reference)
//
#include <hip/hip_runtime.h>
#include <hip/hip_bf16.h>

typedef unsigned short u16;
typedef unsigned int u32;

#define AGT 8
#define NBATCH 32768
#define DDIM 128
#define HEADS 4
#define KDIM 32

typedef float f32x4 __attribute__((ext_vector_type(4)));
typedef __bf16 bf16x8 __attribute__((ext_vector_type(8)));
typedef short s16x8 __attribute__((ext_vector_type(8)));
typedef u32 u32x4 __attribute__((ext_vector_type(4)));

union FragU { s16x8 s; bf16x8 b; u32x4 u; };

__device__ __forceinline__ u16 f2bf(float f) {
  u32 u = __float_as_uint(f);
  u = (u + 0x7FFFu + ((u >> 16) & 1u)) >> 16;
  return (u16)u;
}

// Rearrange W[h][k][d] (f32) into bf16 MFMA fragment order (A- or B-side,
// same map): Wb[(((pj*8+t)*4+kc)*64+l)*8+b] = W_pj[c>>5][c&31][d],
//   c = t*16 + (l&15),  d = kc*32 + (b>>2)*16 + ((l>>4)<<2) + (b&3)
__global__ void prep_weights(const float* __restrict__ Wk,
                             const float* __restrict__ Ws,
                             const float* __restrict__ Wv,
                             u16* __restrict__ Wb) {
  int idx = blockIdx.x * 256 + threadIdx.x;
  if (idx >= 3 * 8 * 4 * 64 * 8) return;
  int b  = idx & 7;
  int l  = (idx >> 3) & 63;
  int kc = (idx >> 9) & 3;
  int t  = (idx >> 11) & 7;
  int pj = idx >> 14;
  int c = t * 16 + (l & 15);
  int h = c >> 5, kk = c & 31;
  int d = kc * 32 + ((b >> 2) << 4) + ((l >> 4) << 2) + (b & 3);
  const float* W = (pj == 0) ? Wk : ((pj == 1) ? Ws : Wv);
  Wb[idx] = f2bf(W[(h * KDIM + kk) * DDIM + d]);
}

// Issue one X row's 8 float4 loads (no conversion — keep them in flight).
__device__ __forceinline__ void issue8(const float* __restrict__ rowp, int lg,
                                       float4 r[8]) {
#pragma unroll
  for (int kc = 0; kc < 4; ++kc) {
    r[kc * 2]     = *(const float4*)(rowp + kc * 32 + lg * 4);
    r[kc * 2 + 1] = *(const float4*)(rowp + kc * 32 + lg * 4 + 16);
  }
}

// Convert 8 raw float4 into 4 bf16x8 fragments (compiler emits packed cvt).
__device__ __forceinline__ void cvt8(const float4 r[8], FragU f[4]) {
#pragma unroll
  for (int kc = 0; kc < 4; ++kc) {
    const float4 x0 = r[kc * 2];
    const float4 x1 = r[kc * 2 + 1];
    FragU t;
    t.b[0] = (__bf16)x0.x; t.b[1] = (__bf16)x0.y;
    t.b[2] = (__bf16)x0.z; t.b[3] = (__bf16)x0.w;
    t.b[4] = (__bf16)x1.x; t.b[5] = (__bf16)x1.y;
    t.b[6] = (__bf16)x1.z; t.b[7] = (__bf16)x1.w;
    f[kc] = t;
  }
}

// Transposed projection: out4[h] = A-frag rows of (W . X^T) for head pairs.
template <int PJ>
__device__ __forceinline__ void projT(const FragU fx[4],
                                      const u16* __restrict__ Wb, int l,
                                      FragU out4[HEADS]) {
  const f32x4 zero4 = (f32x4)(0.0f);
#pragma unroll
  for (int g = 0; g < 2; ++g) {
    f32x4 a[4];
#pragma unroll
    for (int m4 = 0; m4 < 4; ++m4) {
      a[m4] = zero4;
      const int mt = g * 4 + m4;
#pragma unroll
      for (int kc = 0; kc < 4; ++kc) {
        FragU fb;
        fb.s = *(const s16x8*)(Wb + ((((PJ * 8 + mt) * 4 + kc) * 64 + l) << 3));
        a[m4] = __builtin_amdgcn_mfma_f32_16x16x32_bf16(fb.b, fx[kc].b, a[m4],
                                                        0, 0, 0);
      }
    }
#pragma unroll
    for (int hh = 0; hh < 2; ++hh) {
      FragU t;
      t.b[0] = (__bf16)a[2 * hh][0];     t.b[1] = (__bf16)a[2 * hh][1];
      t.b[2] = (__bf16)a[2 * hh][2];     t.b[3] = (__bf16)a[2 * hh][3];
      t.b[4] = (__bf16)a[2 * hh + 1][0]; t.b[5] = (__bf16)a[2 * hh + 1][1];
      t.b[6] = (__bf16)a[2 * hh + 1][2]; t.b[7] = (__bf16)a[2 * hh + 1][3];
      out4[g * 2 + hh] = t;
    }
  }
}

// Normal-orientation V projection + bias + leaky relu -> PV B-frags.
__device__ __forceinline__ void projV(const FragU fx[4],
                                      const u16* __restrict__ Wb, int l,
                                      const float biasr[8], FragU hv4[8]) {
  const f32x4 zero4 = (f32x4)(0.0f);
#pragma unroll
  for (int ct = 0; ct < 8; ++ct) {
    f32x4 a = zero4;
#pragma unroll
    for (int kc = 0; kc < 4; ++kc) {
      FragU fb;
      fb.s = *(const s16x8*)(Wb + ((((2 * 8 + ct) * 4 + kc) * 64 + l) << 3));
      a = __builtin_amdgcn_mfma_f32_16x16x32_bf16(fx[kc].b, fb.b, a, 0, 0, 0);
    }
    FragU t;
#pragma unroll
    for (int rg = 0; rg < 4; ++rg) {
      float v = a[rg] + biasr[ct];
      v = (v > 0.0f) ? v : 0.01f * v;
      t.b[rg] = (__bf16)v;
    }
    t.u[2] = 0;
    t.u[3] = 0;
    hv4[ct] = t;
  }
}

__global__ __launch_bounds__(256, 2) void fused_attn(
    const float* __restrict__ qin, const float* __restrict__ kin,
    const float* __restrict__ vin, const u16* __restrict__ Wb,
    const float* __restrict__ bv,
    float* __restrict__ out0, float* __restrict__ out1,
    float* __restrict__ out2) {
  const int tid = threadIdx.x;
  const int l = tid & 63;
  const int w = tid >> 6;
  const int lr = l & 15;
  const int lg = l >> 4;
  // persistent wave: owns 8 consecutive n, processed as 4 iters x 2 n
  const int gw = blockIdx.x * 4 + w;
  const int nw = gw * 8;
  const int my_agent = lr >> 1;
  const int ipar = lr & 1;
  const size_t xoff =
      ((size_t)my_agent * NBATCH + (size_t)(nw + ipar)) * DDIM;
  const float* pk = kin + xoff;
  const float* pq = qin + xoff;
  const float* pv = vin + xoff;

  float biasr[8];
#pragma unroll
  for (int ct = 0; ct < 8; ++ct) biasr[ct] = bv[ct * 16 + lr];

  // prologue: put iter-0's 24 X loads in flight
  float4 rK[8], rQ[8], rV[8];
  issue8(pk, lg, rK);
  issue8(pq, lg, rQ);
  issue8(pv, lg, rV);

  const f32x4 zero4 = (f32x4)(0.0f);
  const float scale = 0.17677669529663687f;  // 1/sqrt(32)

  for (int it = 0; it < 4; ++it) {
    // consume this iter's X loads (oldest outstanding vmem -> single wait)
    FragU fxK[4], fxQ[4], fxV[4];
    cvt8(rK, fxK);
    cvt8(rQ, fxQ);
    cvt8(rV, fxV);

    // projections (Wb loads are L2-hot; no older slow loads pending)
    FragU hk4[HEADS], hs4[HEADS], hv4[8];
    projT<0>(fxK, Wb, l, hk4);
    projT<1>(fxQ, Wb, l, hs4);
    projV(fxV, Wb, l, biasr, hv4);

    // prefetch next iter's X batch; consumed only at next loop top
    if (it < 3) {
      pk += 2 * DDIM;
      pq += 2 * DDIM;
      pv += 2 * DDIM;
      issue8(pk, lg, rK);
      issue8(pq, lg, rQ);
      issue8(pv, lg, rV);
    }

    // all four S^T tiles first (frees hk4/hs4 early):
    // lane holds S^T(j=4*lg+rg, i=lr); valid iff parity(j)==parity(i)
    f32x4 S[HEADS];
#pragma unroll
    for (int h = 0; h < HEADS; ++h)
      S[h] = __builtin_amdgcn_mfma_f32_16x16x32_bf16(hk4[h].b, hs4[h].b,
                                                     zero4, 0, 0, 0);

    const int n_i = nw + it * 2 + ipar;
    const int a_i = my_agent;

#pragma unroll
    for (int h = 0; h < HEADS; ++h) {
      float sl[4];
#pragma unroll
      for (int rg = 0; rg < 4; ++rg) {
        const int jrow = 4 * lg + rg;
        const bool valid = ((rg & 1) == ipar) && (jrow != lr);
        sl[rg] = valid ? S[h][rg] * scale : -1e30f;
      }
      float mp = fmaxf(fmaxf(sl[0], sl[1]), fmaxf(sl[2], sl[3]));
      mp = fmaxf(mp, __shfl_xor(mp, 16));
      mp = fmaxf(mp, __shfl_xor(mp, 32));
      float e[4];
      float sp = 0.0f;
#pragma unroll
      for (int rg = 0; rg < 4; ++rg) {
        e[rg] = __expf(sl[rg] - mp);  // invalid -> exp(-huge) == 0
        sp += e[rg];
      }
      sp += __shfl_xor(sp, 16);
      sp += __shfl_xor(sp, 32);
      const float inv = 1.0f / sp;
      float p[4];
#pragma unroll
      for (int rg = 0; rg < 4; ++rg) p[rg] = e[rg] * inv;

      // out1 (raw logits) / out2 (probs): writer = lane holding that j
      const size_t ob7 =
          ((size_t)(a_i * HEADS + h) * NBATCH + (size_t)n_i) * 7;
#pragma unroll
      for (int rg = 0; rg < 4; ++rg) {
        const int jrow = 4 * lg + rg;
        if (((rg & 1) == ipar) && (jrow != lr)) {
          const int a_j = jrow >> 1;
          const int jj = a_j - ((a_j > a_i) ? 1 : 0);
          out1[ob7 + jj] = S[h][rg];  // UNSCALED logits
          out2[ob7 + jj] = p[rg];
        }
      }

      // PV: O = P(16x16, zero-masked) . hv ; K zero-padded to 32
      FragU P;
      P.b[0] = (__bf16)p[0]; P.b[1] = (__bf16)p[1];
      P.b[2] = (__bf16)p[2]; P.b[3] = (__bf16)p[3];
      P.u[2] = 0;
      P.u[3] = 0;
      f32x4 O0 = __builtin_amdgcn_mfma_f32_16x16x32_bf16(P.b, hv4[2 * h].b,
                                                         zero4, 0, 0, 0);
      f32x4 O1 = __builtin_amdgcn_mfma_f32_16x16x32_bf16(P.b, hv4[2 * h + 1].b,
                                                         zero4, 0, 0, 0);
      // lane holds O(i_row=4*lg+rg, d = half*16 + lr)
#pragma unroll
      for (int rg = 0; rg < 4; ++rg) {
        const int irow = 4 * lg + rg;
        const int a_o = irow >> 1;
        const int n_o = nw + it * 2 + (irow & 1);
        const size_t o0 =
            ((size_t)(a_o * HEADS + h) * NBATCH + (size_t)n_o) * KDIM;
        out0[o0 + lr] = O0[rg];
        out0[o0 + 16 + lr] = O1[rg];
      }
    }
  }
}

extern "C" void kernel_launch(void* const* d_in, const int* in_sizes, int n_in,
                              void* d_out, int out_size, void* d_ws,
                              size_t ws_size, hipStream_t stream) {
  const float* qin = (const float*)d_in[0];
  const float* kin = (const float*)d_in[1];
  const float* vin = (const float*)d_in[2];
  const float* Wk  = (const float*)d_in[3];
  const float* Ws  = (const float*)d_in[4];
  const float* Wv  = (const float*)d_in[5];
  const float* bvp = (const float*)d_in[6];

  float* out0 = (float*)d_out;
  float* out1 = out0 + (size_t)AGT * HEADS * NBATCH * KDIM;
  float* out2 = out1 + (size_t)AGT * HEADS * NBATCH * 7;

  u16* Wb = (u16*)d_ws;  // 98304 bytes needed

  prep_weights<<<dim3(192), dim3(256), 0, stream>>>(Wk, Ws, Wv, Wb);
  // 1024 blocks x 4 waves; each wave = 8 agents x 8 n (4 pipelined iters)
  fused_attn<<<dim3(1024), dim3(256), 0, stream>>>(
      qin, kin, vin, Wb, bvp, out0, out1, out2);
}

// Round 7
// 232.210 us; speedup vs baseline: 2.7176x; 2.7176x over previous
//
#include <hip/hip_runtime.h>
#include <hip/hip_bf16.h>

typedef unsigned short u16;
typedef unsigned int u32;

#define AGT 8
#define NBATCH 32768
#define DDIM 128
#define HEADS 4
#define KDIM 32

typedef float f32x4 __attribute__((ext_vector_type(4)));
typedef __bf16 bf16x8 __attribute__((ext_vector_type(8)));
typedef short s16x8 __attribute__((ext_vector_type(8)));
typedef u32 u32x4 __attribute__((ext_vector_type(4)));

union FragU { s16x8 s; bf16x8 b; u32x4 u; };

__device__ __forceinline__ u16 f2bf(float f) {
  u32 u = __float_as_uint(f);
  u = (u + 0x7FFFu + ((u >> 16) & 1u)) >> 16;
  return (u16)u;
}

// Rearrange W[h][k][d] (f32) into bf16 MFMA fragment order (A- or B-side,
// same map): Wb[(((pj*8+t)*4+kc)*64+l)*8+b] = W_pj[c>>5][c&31][d],
//   c = t*16 + (l&15),  d = kc*32 + (b>>2)*16 + ((l>>4)<<2) + (b&3)
__global__ void prep_weights(const float* __restrict__ Wk,
                             const float* __restrict__ Ws,
                             const float* __restrict__ Wv,
                             u16* __restrict__ Wb) {
  int idx = blockIdx.x * 256 + threadIdx.x;
  if (idx >= 3 * 8 * 4 * 64 * 8) return;
  int b  = idx & 7;
  int l  = (idx >> 3) & 63;
  int kc = (idx >> 9) & 3;
  int t  = (idx >> 11) & 7;
  int pj = idx >> 14;
  int c = t * 16 + (l & 15);
  int h = c >> 5, kk = c & 31;
  int d = kc * 32 + ((b >> 2) << 4) + ((l >> 4) << 2) + (b & 3);
  const float* W = (pj == 0) ? Wk : ((pj == 1) ? Ws : Wv);
  Wb[idx] = f2bf(W[(h * KDIM + kk) * DDIM + d]);
}

// Issue one X row's 8 float4 loads.
__device__ __forceinline__ void issue8(const float* __restrict__ rowp, int lg,
                                       float4 r[8]) {
#pragma unroll
  for (int kc = 0; kc < 4; ++kc) {
    r[kc * 2]     = *(const float4*)(rowp + kc * 32 + lg * 4);
    r[kc * 2 + 1] = *(const float4*)(rowp + kc * 32 + lg * 4 + 16);
  }
}

// Convert 8 raw float4 into 4 bf16x8 fragments (compiler emits packed cvt).
__device__ __forceinline__ void cvt8(const float4 r[8], FragU f[4]) {
#pragma unroll
  for (int kc = 0; kc < 4; ++kc) {
    const float4 x0 = r[kc * 2];
    const float4 x1 = r[kc * 2 + 1];
    FragU t;
    t.b[0] = (__bf16)x0.x; t.b[1] = (__bf16)x0.y;
    t.b[2] = (__bf16)x0.z; t.b[3] = (__bf16)x0.w;
    t.b[4] = (__bf16)x1.x; t.b[5] = (__bf16)x1.y;
    t.b[6] = (__bf16)x1.z; t.b[7] = (__bf16)x1.w;
    f[kc] = t;
  }
}

__device__ __forceinline__ FragU pack2(const f32x4 lo, const f32x4 hi) {
  FragU t;
  t.b[0] = (__bf16)lo[0]; t.b[1] = (__bf16)lo[1];
  t.b[2] = (__bf16)lo[2]; t.b[3] = (__bf16)lo[3];
  t.b[4] = (__bf16)hi[0]; t.b[5] = (__bf16)hi[1];
  t.b[6] = (__bf16)hi[2]; t.b[7] = (__bf16)hi[3];
  return t;
}

// Transposed projection, TWO batch tiles sharing each weight fragment load.
template <int PJ>
__device__ __forceinline__ void projT2(const FragU fx0[4], const FragU fx1[4],
                                       const u16* __restrict__ Wb, int l,
                                       FragU o0[HEADS], FragU o1[HEADS]) {
  const f32x4 z = (f32x4)(0.0f);
#pragma unroll
  for (int g = 0; g < 2; ++g) {
    f32x4 a0[4], a1[4];
#pragma unroll
    for (int m4 = 0; m4 < 4; ++m4) {
      a0[m4] = z;
      a1[m4] = z;
      const int mt = g * 4 + m4;
#pragma unroll
      for (int kc = 0; kc < 4; ++kc) {
        FragU fb;
        fb.s = *(const s16x8*)(Wb + ((((PJ * 8 + mt) * 4 + kc) * 64 + l) << 3));
        a0[m4] = __builtin_amdgcn_mfma_f32_16x16x32_bf16(fb.b, fx0[kc].b,
                                                         a0[m4], 0, 0, 0);
        a1[m4] = __builtin_amdgcn_mfma_f32_16x16x32_bf16(fb.b, fx1[kc].b,
                                                         a1[m4], 0, 0, 0);
      }
    }
#pragma unroll
    for (int hh = 0; hh < 2; ++hh) {
      o0[g * 2 + hh] = pack2(a0[2 * hh], a0[2 * hh + 1]);
      o1[g * 2 + hh] = pack2(a1[2 * hh], a1[2 * hh + 1]);
    }
  }
}

// Normal-orientation V projection + bias + leaky relu, two tiles, compact
// output (only k-slots 0..3 are nonzero -> store 2 dwords per ct per tile).
__device__ __forceinline__ void projV2(const FragU fx0[4], const FragU fx1[4],
                                       const u16* __restrict__ Wb, int l,
                                       const float biasr[8],
                                       u32 hv0[8][2], u32 hv1[8][2]) {
  const f32x4 z = (f32x4)(0.0f);
#pragma unroll
  for (int ct = 0; ct < 8; ++ct) {
    f32x4 a0 = z, a1 = z;
#pragma unroll
    for (int kc = 0; kc < 4; ++kc) {
      FragU fb;
      fb.s = *(const s16x8*)(Wb + ((((16 + ct) * 4 + kc) * 64 + l) << 3));
      a0 = __builtin_amdgcn_mfma_f32_16x16x32_bf16(fx0[kc].b, fb.b, a0, 0, 0, 0);
      a1 = __builtin_amdgcn_mfma_f32_16x16x32_bf16(fx1[kc].b, fb.b, a1, 0, 0, 0);
    }
    const float bb = biasr[ct];
    {
      float x0 = a0[0] + bb, x1 = a0[1] + bb, x2 = a0[2] + bb, x3 = a0[3] + bb;
      x0 = (x0 > 0.f) ? x0 : 0.01f * x0;
      x1 = (x1 > 0.f) ? x1 : 0.01f * x1;
      x2 = (x2 > 0.f) ? x2 : 0.01f * x2;
      x3 = (x3 > 0.f) ? x3 : 0.01f * x3;
      FragU t;
      t.b[0] = (__bf16)x0; t.b[1] = (__bf16)x1;
      t.b[2] = (__bf16)x2; t.b[3] = (__bf16)x3;
      hv0[ct][0] = t.u[0];
      hv0[ct][1] = t.u[1];
    }
    {
      float x0 = a1[0] + bb, x1 = a1[1] + bb, x2 = a1[2] + bb, x3 = a1[3] + bb;
      x0 = (x0 > 0.f) ? x0 : 0.01f * x0;
      x1 = (x1 > 0.f) ? x1 : 0.01f * x1;
      x2 = (x2 > 0.f) ? x2 : 0.01f * x2;
      x3 = (x3 > 0.f) ? x3 : 0.01f * x3;
      FragU t;
      t.b[0] = (__bf16)x0; t.b[1] = (__bf16)x1;
      t.b[2] = (__bf16)x2; t.b[3] = (__bf16)x3;
      hv1[ct][0] = t.u[0];
      hv1[ct][1] = t.u[1];
    }
  }
}

__global__ __launch_bounds__(256, 3) void fused_attn(
    const float* __restrict__ qin, const float* __restrict__ kin,
    const float* __restrict__ vin, const u16* __restrict__ Wb,
    const float* __restrict__ bv,
    float* __restrict__ out0, float* __restrict__ out1,
    float* __restrict__ out2) {
  const int tid = threadIdx.x;
  const int l = tid & 63;
  const int w = tid >> 6;
  const int lr = l & 15;
  const int lg = l >> 4;
  // wave owns 4 consecutive n as two 16-row tiles (8 agents x 2 n each)
  const int nbase = (blockIdx.x * 4 + w) * 4;
  const int my_agent = lr >> 1;
  const int ipar = lr & 1;
  const size_t xoff0 =
      ((size_t)my_agent * NBATCH + (size_t)(nbase + ipar)) * DDIM;
  const size_t xoff1 = xoff0 + 2 * DDIM;

  float biasr[8];
#pragma unroll
  for (int ct = 0; ct < 8; ++ct) biasr[ct] = bv[ct * 16 + lr];

  const f32x4 zero4 = (f32x4)(0.0f);
  const float scale = 0.17677669529663687f;  // 1/sqrt(32)

  FragU hk[2][HEADS], hs[2][HEADS];
  u32 hv[2][8][2];

  // ---- K projection (transposed), both tiles ----
  {
    float4 rA[8], rB[8];
    issue8(kin + xoff0, lg, rA);
    issue8(kin + xoff1, lg, rB);
    FragU fx0[4], fx1[4];
    cvt8(rA, fx0);
    cvt8(rB, fx1);
    projT2<0>(fx0, fx1, Wb, l, hk[0], hk[1]);
  }
  // ---- Q/selector projection (transposed), both tiles ----
  {
    float4 rA[8], rB[8];
    issue8(qin + xoff0, lg, rA);
    issue8(qin + xoff1, lg, rB);
    FragU fx0[4], fx1[4];
    cvt8(rA, fx0);
    cvt8(rB, fx1);
    projT2<1>(fx0, fx1, Wb, l, hs[0], hs[1]);
  }
  // ---- V projection (normal) + bias + leaky, both tiles ----
  {
    float4 rA[8], rB[8];
    issue8(vin + xoff0, lg, rA);
    issue8(vin + xoff1, lg, rB);
    FragU fx0[4], fx1[4];
    cvt8(rA, fx0);
    cvt8(rB, fx1);
    projV2(fx0, fx1, Wb, l, biasr, hv[0], hv[1]);
  }

  // ---- S^T for all tiles/heads first (kills hk/hs liveness) ----
  // lane holds S^T(j=4*lg+rg, i=lr); valid iff parity(j)==parity(i)
  f32x4 S[2][HEADS];
#pragma unroll
  for (int t = 0; t < 2; ++t)
#pragma unroll
    for (int h = 0; h < HEADS; ++h)
      S[t][h] = __builtin_amdgcn_mfma_f32_16x16x32_bf16(hk[t][h].b, hs[t][h].b,
                                                        zero4, 0, 0, 0);

  const int a_i = my_agent;
#pragma unroll
  for (int t = 0; t < 2; ++t) {
    const int n_i = nbase + 2 * t + ipar;
#pragma unroll
    for (int h = 0; h < HEADS; ++h) {
      float sl[4];
#pragma unroll
      for (int rg = 0; rg < 4; ++rg) {
        const int jrow = 4 * lg + rg;
        const bool valid = ((rg & 1) == ipar) && (jrow != lr);
        sl[rg] = valid ? S[t][h][rg] * scale : -1e30f;
      }
      float mp = fmaxf(fmaxf(sl[0], sl[1]), fmaxf(sl[2], sl[3]));
      mp = fmaxf(mp, __shfl_xor(mp, 16));
      mp = fmaxf(mp, __shfl_xor(mp, 32));
      float e[4];
      float sp = 0.0f;
#pragma unroll
      for (int rg = 0; rg < 4; ++rg) {
        e[rg] = __expf(sl[rg] - mp);  // invalid -> exp(-huge) == 0
        sp += e[rg];
      }
      sp += __shfl_xor(sp, 16);
      sp += __shfl_xor(sp, 32);
      const float inv = 1.0f / sp;
      float p[4];
#pragma unroll
      for (int rg = 0; rg < 4; ++rg) p[rg] = e[rg] * inv;

      // out1 (raw logits) / out2 (probs): writer = lane holding that j
      const size_t ob7 =
          ((size_t)(a_i * HEADS + h) * NBATCH + (size_t)n_i) * 7;
#pragma unroll
      for (int rg = 0; rg < 4; ++rg) {
        const int jrow = 4 * lg + rg;
        if (((rg & 1) == ipar) && (jrow != lr)) {
          const int a_j = jrow >> 1;
          const int jj = a_j - ((a_j > a_i) ? 1 : 0);
          out1[ob7 + jj] = S[t][h][rg];  // UNSCALED logits
          out2[ob7 + jj] = p[rg];
        }
      }

      // PV: O = P(16x16, zero-masked) . hv ; K zero-padded to 32
      FragU P;
      P.b[0] = (__bf16)p[0]; P.b[1] = (__bf16)p[1];
      P.b[2] = (__bf16)p[2]; P.b[3] = (__bf16)p[3];
      P.u[2] = 0;
      P.u[3] = 0;
      FragU B0, B1;
      B0.u[0] = hv[t][2 * h][0];     B0.u[1] = hv[t][2 * h][1];
      B0.u[2] = 0;                   B0.u[3] = 0;
      B1.u[0] = hv[t][2 * h + 1][0]; B1.u[1] = hv[t][2 * h + 1][1];
      B1.u[2] = 0;                   B1.u[3] = 0;
      f32x4 O0 = __builtin_amdgcn_mfma_f32_16x16x32_bf16(P.b, B0.b, zero4,
                                                         0, 0, 0);
      f32x4 O1 = __builtin_amdgcn_mfma_f32_16x16x32_bf16(P.b, B1.b, zero4,
                                                         0, 0, 0);
      // lane holds O(i_row=4*lg+rg, d = half*16 + lr)
#pragma unroll
      for (int rg = 0; rg < 4; ++rg) {
        const int irow = 4 * lg + rg;
        const int a_o = irow >> 1;
        const int n_o = nbase + 2 * t + (irow & 1);
        const size_t o0 =
            ((size_t)(a_o * HEADS + h) * NBATCH + (size_t)n_o) * KDIM;
        out0[o0 + lr] = O0[rg];
        out0[o0 + 16 + lr] = O1[rg];
      }
    }
  }
}

extern "C" void kernel_launch(void* const* d_in, const int* in_sizes, int n_in,
                              void* d_out, int out_size, void* d_ws,
                              size_t ws_size, hipStream_t stream) {
  const float* qin = (const float*)d_in[0];
  const float* kin = (const float*)d_in[1];
  const float* vin = (const float*)d_in[2];
  const float* Wk  = (const float*)d_in[3];
  const float* Ws  = (const float*)d_in[4];
  const float* Wv  = (const float*)d_in[5];
  const float* bvp = (const float*)d_in[6];

  float* out0 = (float*)d_out;
  float* out1 = out0 + (size_t)AGT * HEADS * NBATCH * KDIM;
  float* out2 = out1 + (size_t)AGT * HEADS * NBATCH * 7;

  u16* Wb = (u16*)d_ws;  // 98304 bytes needed

  prep_weights<<<dim3(192), dim3(256), 0, stream>>>(Wk, Ws, Wv, Wb);
  // 2048 blocks x 4 waves; each wave = 8 agents x 4 n (two 16-row tiles)
  fused_attn<<<dim3(2048), dim3(256), 0, stream>>>(
      qin, kin, vin, Wb, bvp, out0, out1, out2);
}